// Round 6
// baseline (6605.237 us; speedup 1.0000x reference)
//
#include <hip/hip_runtime.h>

// Graph-gated LSTM recurrence, persistent cooperative kernel (round 9).
// R8 post-mortem: 6.01ms = 16.5us/step (predicted 13-16, weak match).
// Occupancy 24.7% = 2 waves/SIMD; VGPR=128 admits 4/SIMD. Serial accounting
// still ~2x under measurement -> remaining exposed latency + LLC contention
// (every CU re-reads all 320KB of X per step from LLC; flag hops ride the
// same fabric). Also: R8 had EVERY wave polling the 16 gflag lines (2048
// pollers) -- only raw-flag fan-in was fixed. This round, zero new
// primitives:
//  1. 1024 threads = 16 waves = 4 waves/SIMD (KSPL=256, NFRG=8, afrag 32
//     VGPR, launch_bounds(1024,4)). 2x latency hiding everywhere.
//  2. Single-wave gate: wave 0 polls gflags, rest wait at __syncthreads.
//     16x fewer gflag pollers device-wide.
//  3. x(t+1) prefetch hoisted above the gate (latency overlaps the poll).
// Sync structure otherwise IDENTICAL to proven R7/R8 (write-through X at
// LLC, generation-indexed addresses, two-level flag tree, no fences).
// Predicted: 16.5us/step -> 12-14us/step. If <10% gain, TLP is exhausted ->
// pivot to LLC-contention attack (per-XCD staging) next round.

#define NN   4096
#define TT   365
#define FF   16
#define HH   20
#define G4   80
#define RPB  16     // nodes per block
#define NBLK 256
#define NTHR 1024   // 16 waves, 4 per SIMD
#define NWV  16
#define XRG  42     // rows per generation: 40 data + 1 pad(read) + 1 guard
#define KSPL 256    // K-slice per wave (16 waves * 256 = 4096)
#define NFRG 8      // A fragments per wave (KSPL/32)
#define NGRP 16     // relay groups (16 blocks each)

typedef float f4 __attribute__((ext_vector_type(4)));
typedef short s8v __attribute__((ext_vector_type(8)));

// 365 generations * 42 rows * 4096 cols * 2B = 125.6MB; lives in LLC.
__device__ __attribute__((aligned(16))) unsigned short g_X[(size_t)TT * XRG * NN];
__device__ unsigned g_flag[NBLK];        // raw: block b published X(gen)
__device__ unsigned g_gflag[NGRP * 32];  // group flags, 128B apart

struct __align__(16) Smem {
  float WkT[G4][FF];              // lstm kernel, transposed
  float WrT[G4][HH];              // lstm recurrent, transposed
  float WghT[HH][HH]; float WgcT[HH][HH];
  float WhcT[HH][HH]; float WhpT[HH][HH];
  float WccT[HH][HH]; float WcpT[HH][HH];
  float Wout[HH];
  float bias[G4];
  float bgh[HH]; float bgc[HH]; float bhv[HH]; float bcv[HH];
  float bout; float pad0[3];
  float hprev[RPB][HH]; float cprev[RPB][HH];
  float hcur[RPB][HH];  float ccur[RPB][HH];
  float hg[RPB][HH];    float cg[RPB][HH];
  float cen[2 * HH];              // X centering values
  float SA[RPB];                  // per-row sum of bf16(A)
  float sAp[64][16];              // 16 waves * 4 quads
  float part[NWV][3][16][17];     // per-wave MFMA partials (~52KB)
};                                // ~86 KB total (1 block/CU; 160KB LDS)

__device__ inline float sigm(float x) { return 1.f / (1.f + __expf(-x)); }
__device__ inline float tanh_f(float x) { return 2.f / (1.f + __expf(-2.f * x)) - 1.f; }

__device__ inline unsigned short f2bf(float f) {   // RNE fp32->bf16
  unsigned u = __float_as_uint(f);
  u = u + 0x7FFFu + ((u >> 16) & 1u);
  return (unsigned short)(u >> 16);
}
__device__ inline float bf2f(unsigned short u) {
  return __uint_as_float(((unsigned)u) << 16);
}

__device__ inline void load_x(const float* __restrict__ inputs, int nb0, int t,
                              int tid, f4* x) {
  const float* xr = inputs + ((size_t)(nb0 + (tid & 15)) * TT + t) * FF;
  x[0] = *(const f4*)(xr);
  x[1] = *(const f4*)(xr + 4);
  x[2] = *(const f4*)(xr + 8);
  x[3] = *(const f4*)(xr + 12);
}

// LSTM cell for the block's 16 nodes; x pre-loaded for node tid&15.
__device__ inline void lstm_cells_x(Smem& sm, const f4* x, int tid) {
  const int n = tid & 15;
  const f4* hpr = (const f4*)sm.hprev[n];
  const f4 hp0 = hpr[0], hp1 = hpr[1], hp2 = hpr[2], hp3 = hpr[3], hp4 = hpr[4];
  for (int idx = tid; idx < RPB * HH; idx += NTHR) {
    const int h = idx >> 4;
    float z[4];
#pragma unroll
    for (int g = 0; g < 4; g++) {
      const int col = g * HH + h;
      const f4* wk = (const f4*)sm.WkT[col];
      f4 acc = x[0] * wk[0] + x[1] * wk[1] + x[2] * wk[2] + x[3] * wk[3];
      const f4* wr = (const f4*)sm.WrT[col];
      acc += hp0 * wr[0] + hp1 * wr[1] + hp2 * wr[2] + hp3 * wr[3] + hp4 * wr[4];
      z[g] = sm.bias[col] + acc[0] + acc[1] + acc[2] + acc[3];
    }
    const float co = sm.cprev[n][h];
    const float cn = sigm(z[1]) * co + sigm(z[0]) * tanh_f(z[2]);
    const float hn = sigm(z[3]) * tanh_f(cn);
    sm.hcur[n][h] = hn;
    sm.ccur[n][h] = cn;
  }
}

// X^T[j][node] (bf16, centered) for generation `gen`, from current hprev/cprev.
// Agent-scope write-through stores: X lives only at the LLC, never dirty in L2.
__device__ inline void produce_X(Smem& sm, int gen, int nb0, int tid) {
  for (int idx = tid; idx < 8 * 2 * HH; idx += NTHR) {   // 320 items
    const int p = idx & 7, j = idx >> 3;                 // j in [0,40)
    const int n0 = p * 2;
    const f4* w; float b0; const f4* s0; const f4* s1;
    if (j < HH) {
      w = (const f4*)sm.WghT[j];     b0 = sm.bgh[j];
      s0 = (const f4*)sm.hprev[n0];  s1 = (const f4*)sm.hprev[n0 + 1];
    } else {
      w = (const f4*)sm.WgcT[j-HH];  b0 = sm.bgc[j - HH];
      s0 = (const f4*)sm.cprev[n0];  s1 = (const f4*)sm.cprev[n0 + 1];
    }
    const f4 w0 = w[0], w1 = w[1], w2 = w[2], w3 = w[3], w4 = w[4];
    f4 a0 = s0[0]*w0 + s0[1]*w1 + s0[2]*w2 + s0[3]*w3 + s0[4]*w4;
    f4 a1 = s1[0]*w0 + s1[1]*w1 + s1[2]*w2 + s1[3]*w3 + s1[4]*w4;
    const float c0 = sm.cen[j];
    const unsigned short lo = f2bf(b0 + a0[0] + a0[1] + a0[2] + a0[3] - c0);
    const unsigned short hi = f2bf(b0 + a1[0] + a1[1] + a1[2] + a1[3] - c0);
    const unsigned v = (unsigned)lo | ((unsigned)hi << 16);
    unsigned* dst = (unsigned*)(g_X + (((size_t)gen * XRG + j) << 12) + (unsigned)(nb0 + n0));
    __hip_atomic_store(dst, v, __ATOMIC_RELAXED, __HIP_MEMORY_SCOPE_AGENT);
  }
}

// All X stores of this block drained to the coherence point, then one flag.
__device__ inline void publish(int tid, unsigned gen) {
  asm volatile("s_waitcnt vmcnt(0)" ::: "memory");  // write-through stores at LLC
  __syncthreads();                                  // all waves drained
  if (tid == 0)
    __hip_atomic_store(&g_flag[blockIdx.x], gen,
                       __ATOMIC_RELAXED, __HIP_MEMORY_SCOPE_AGENT);
}

__global__ void bar_init() {
  const int i = threadIdx.x;
  if (i < NBLK)
    __hip_atomic_store(&g_flag[i], 0u, __ATOMIC_RELAXED, __HIP_MEMORY_SCOPE_AGENT);
  if (i < NGRP)
    __hip_atomic_store(&g_gflag[i * 32], 0u, __ATOMIC_RELAXED, __HIP_MEMORY_SCOPE_AGENT);
}

__global__ void __launch_bounds__(NTHR, 4)
gg_kernel(const float* __restrict__ inputs, const float* __restrict__ Ag,
          const float* __restrict__ Wk, const float* __restrict__ Wr, const float* __restrict__ bls,
          const float* __restrict__ Wgh, const float* __restrict__ bgh,
          const float* __restrict__ Wgc, const float* __restrict__ bgc,
          const float* __restrict__ Whc, const float* __restrict__ Whp, const float* __restrict__ bh,
          const float* __restrict__ Wcc, const float* __restrict__ Wcp, const float* __restrict__ bc,
          const float* __restrict__ Wo, const float* __restrict__ bo,
          float* __restrict__ out) {
  __shared__ Smem sm;
  const int tid  = threadIdx.x;
  const int nb0  = blockIdx.x * RPB;
  const int lane = tid & 63;
  const int wv   = tid >> 6;          // 0..15
  const int li   = lane & 15;
  const int quad = lane >> 4;

  // ---- one-time: weights (transposed) into LDS ----
  for (int i = tid; i < FF * G4; i += NTHR) sm.WkT[i % G4][i / G4] = Wk[i];
  for (int i = tid; i < HH * G4; i += NTHR) sm.WrT[i % G4][i / G4] = Wr[i];
  for (int i = tid; i < HH * HH; i += NTHR) {
    const int r = i / HH, c = i % HH;
    sm.WghT[c][r] = Wgh[i]; sm.WgcT[c][r] = Wgc[i];
    sm.WhcT[c][r] = Whc[i]; sm.WhpT[c][r] = Whp[i];
    sm.WccT[c][r] = Wcc[i]; sm.WcpT[c][r] = Wcp[i];
  }
  for (int i = tid; i < G4; i += NTHR) sm.bias[i] = bls[i];
  if (tid < HH) { sm.bgh[tid] = bgh[tid]; sm.bgc[tid] = bgc[tid]; sm.bhv[tid] = bh[tid]; sm.bcv[tid] = bc[tid]; sm.Wout[tid] = Wo[tid]; }
  if (tid == 0) sm.bout = bo[0];
  for (int i = tid; i < RPB * HH; i += NTHR) { (&sm.hprev[0][0])[i] = 0.f; (&sm.cprev[0][0])[i] = 0.f; }
  __syncthreads();

  // cen[j] = b[j] + 0.5 * column-sum(W): X values cluster here
  if (tid < 2 * HH) {
    const int j = tid;
    float s = 0.f;
    if (j < HH) { for (int h = 0; h < HH; h++) s += sm.WghT[j][h]; s = sm.bgh[j] + 0.5f * s; }
    else        { for (int h = 0; h < HH; h++) s += sm.WgcT[j - HH][h]; s = sm.bgc[j - HH] + 0.5f * s; }
    sm.cen[j] = s;
  }

  // ---- one-time: A rows -> VGPR fragments (bf16) + row sums of bf16(A) ----
  s8v afrag[NFRG];
  {
    const float* Arow = Ag + (size_t)(nb0 + li) * NN + (size_t)(wv * KSPL + quad * 8);
    double ds = 0.0;
#pragma unroll
    for (int i = 0; i < NFRG; i++) {
      const f4 v0 = *(const f4*)(Arow + i * 32);
      const f4 v1 = *(const f4*)(Arow + i * 32 + 4);
      s8v tb;
      tb[0] = (short)f2bf(v0[0]); tb[1] = (short)f2bf(v0[1]);
      tb[2] = (short)f2bf(v0[2]); tb[3] = (short)f2bf(v0[3]);
      tb[4] = (short)f2bf(v1[0]); tb[5] = (short)f2bf(v1[1]);
      tb[6] = (short)f2bf(v1[2]); tb[7] = (short)f2bf(v1[3]);
      afrag[i] = tb;
#pragma unroll
      for (int e = 0; e < 8; e++) ds += (double)bf2f((unsigned short)tb[e]);
    }
    sm.sAp[wv * 4 + quad][li] = (float)ds;
  }
  __syncthreads();
  if (tid < RPB) {
    float s = 0.f;
#pragma unroll
    for (int g = 0; g < 64; g++) s += sm.sAp[g][tid];
    sm.SA[tid] = s;
  }

  // ---- warm phase: T LSTM steps, block-local, x prefetched one step ahead ----
  f4 xa[4], xb[4];
  load_x(inputs, nb0, 0, tid, xa);
  for (int t = 0; t < TT; t++) {
    if (t + 1 < TT) load_x(inputs, nb0, t + 1, tid, xb);
    __syncthreads();
    lstm_cells_x(sm, xa, tid);
    __syncthreads();
    for (int i = tid; i < RPB * HH; i += NTHR) {
      (&sm.hprev[0][0])[i] = (&sm.hcur[0][0])[i];
      (&sm.cprev[0][0])[i] = (&sm.ccur[0][0])[i];
    }
    xa[0] = xb[0]; xa[1] = xb[1]; xa[2] = xb[2]; xa[3] = xb[3];
  }
  __syncthreads();

  // prologue: publish X_1, then LSTM(t=1) while other blocks finish
  produce_X(sm, 1, nb0, tid);
  publish(tid, 1u);
  load_x(inputs, nb0, 1, tid, xa);
  lstm_cells_x(sm, xa, tid);

  // ---- main recurrence: t = 1..364 ----
  for (int t = 1; t < TT; t++) {
    // prefetch x(t+1) into regs: latency overlaps the gate poll below
    if (t + 1 < TT) load_x(inputs, nb0, t + 1, tid, xa);

    // relay duty: blocks 0..15 aggregate 16 raw flags -> 1 group flag
    if (blockIdx.x < NGRP && wv == 0) {
      const int g = blockIdx.x;
      for (;;) {
        int ok = 1;
        if (lane < 16)
          ok = (__hip_atomic_load(&g_flag[g * 16 + lane], __ATOMIC_RELAXED,
                                  __HIP_MEMORY_SCOPE_AGENT) >= (unsigned)t);
        if (__all(ok)) break;
        __builtin_amdgcn_s_sleep(1);
      }
      if (lane == 0)
        __hip_atomic_store(&g_gflag[g * 32], (unsigned)t,
                           __ATOMIC_RELAXED, __HIP_MEMORY_SCOPE_AGENT);
    }

    // consumer gate: ONLY wave 0 polls; other 15 waves wait at the barrier
    if (wv == 0) {
      for (;;) {
        int ok = 1;
        if (lane < NGRP)
          ok = (__hip_atomic_load(&g_gflag[lane * 32], __ATOMIC_RELAXED,
                                  __HIP_MEMORY_SCOPE_AGENT) >= (unsigned)t);
        if (__all(ok)) break;
        __builtin_amdgcn_s_sleep(1);
      }
    }
    __syncthreads();

    // MFMA partials from generation-t X (fresh addresses, LLC-served misses)
    const unsigned short* Xt = g_X + (((size_t)t * XRG) << 12)
                             + (size_t)(wv * KSPL + quad * 8);
#pragma unroll
    for (int c = 0; c < 3; c++) {
      int row = c * 16 + li;
      if (row >= 2 * HH) row = 2 * HH;   // pad lanes read row 40 (discarded)
      const unsigned short* Xrow = Xt + ((size_t)row << 12);
      f4 a0 = {0.f, 0.f, 0.f, 0.f}, a1 = a0, a2 = a0, a3 = a0;
#pragma unroll
      for (int i = 0; i < NFRG; i += 4) {
        a0 = __builtin_amdgcn_mfma_f32_16x16x32_bf16(afrag[i + 0], *(const s8v*)(Xrow + (i + 0) * 32), a0, 0, 0, 0);
        a1 = __builtin_amdgcn_mfma_f32_16x16x32_bf16(afrag[i + 1], *(const s8v*)(Xrow + (i + 1) * 32), a1, 0, 0, 0);
        a2 = __builtin_amdgcn_mfma_f32_16x16x32_bf16(afrag[i + 2], *(const s8v*)(Xrow + (i + 2) * 32), a2, 0, 0, 0);
        a3 = __builtin_amdgcn_mfma_f32_16x16x32_bf16(afrag[i + 3], *(const s8v*)(Xrow + (i + 3) * 32), a3, 0, 0, 0);
      }
      const f4 ac = (a0 + a1) + (a2 + a3);
#pragma unroll
      for (int r = 0; r < 4; r++) sm.part[wv][c][quad * 4 + r][li] = ac[r];
    }
    __syncthreads();

    // cross-wave reduce (16 partials) + centering + tanh -> hg/cg
    if (tid < 768) {
      const int c = tid >> 8, rc = tid & 255, r = rc >> 4, col = rc & 15;
      const int gc = c * 16 + col;
      if (gc < 2 * HH) {
        float s = 0.f;
#pragma unroll
        for (int w = 0; w < NWV; w++) s += sm.part[w][c][r][col];
        const float v = s + sm.SA[r] * sm.cen[gc];
        const float tv = tanh_f(v);
        if (gc < HH) sm.hg[r][gc] = tv; else sm.cg[r][gc - HH] = tv;
      }
    }
    __syncthreads();

    // update stage: h_upd = sig(hcur@Whc + hg@Whp + bh); c_upd likewise
    for (int idx = tid; idx < 2 * RPB * HH; idx += NTHR) {
      int q = idx; int cpath = 0;
      if (q >= RPB * HH) { q -= RPB * HH; cpath = 1; }
      const int n = q & 15, h = q >> 4;
      const f4* cur = (const f4*)(cpath ? sm.ccur[n] : sm.hcur[n]);
      const f4* gr2 = (const f4*)(cpath ? sm.cg[n] : sm.hg[n]);
      const f4* w1  = (const f4*)(cpath ? sm.WccT[h] : sm.WhcT[h]);
      const f4* w2  = (const f4*)(cpath ? sm.WcpT[h] : sm.WhpT[h]);
      f4 acc = cur[0]*w1[0] + cur[1]*w1[1] + cur[2]*w1[2] + cur[3]*w1[3] + cur[4]*w1[4];
      acc   += gr2[0]*w2[0] + gr2[1]*w2[1] + gr2[2]*w2[2] + gr2[3]*w2[3] + gr2[4]*w2[4];
      const float b0 = cpath ? sm.bcv[h] : sm.bhv[h];
      const float v = sigm(b0 + acc[0] + acc[1] + acc[2] + acc[3]);
      if (cpath) sm.cprev[n][h] = v; else sm.hprev[n][h] = v;
    }
    __syncthreads();

    // publish FIRST (inter-block critical path), out-write after
    if (t < TT - 1) {
      produce_X(sm, t + 1, nb0, tid);              // X generation t+1
      publish(tid, (unsigned)(t + 1));             // drain + flag
    }

    if (tid < RPB) {                               // out[t-1, node] = h_upd @ W_out + b
      float acc = sm.bout;
#pragma unroll
      for (int h2 = 0; h2 < HH; h2++) acc += sm.hprev[tid][h2] * sm.Wout[h2];
      out[(size_t)(t - 1) * NN + nb0 + tid] = acc;
    }

    if (t < TT - 1) {
      lstm_cells_x(sm, xa, tid);                   // LSTM(t+1), x prefetched at top
    }
  }
}

extern "C" void kernel_launch(void* const* d_in, const int* in_sizes, int n_in,
                              void* d_out, int out_size, void* d_ws, size_t ws_size,
                              hipStream_t stream) {
  (void)in_sizes; (void)n_in; (void)out_size; (void)d_ws; (void)ws_size;
  const float* inputs = (const float*)d_in[0];
  const float* Ag     = (const float*)d_in[1];
  const float* Wk     = (const float*)d_in[2];
  const float* Wr     = (const float*)d_in[3];
  const float* bls    = (const float*)d_in[4];
  const float* Wgh    = (const float*)d_in[5];
  const float* bgh    = (const float*)d_in[6];
  const float* Wgc    = (const float*)d_in[7];
  const float* bgc    = (const float*)d_in[8];
  const float* Whc    = (const float*)d_in[9];
  const float* Whp    = (const float*)d_in[10];
  const float* bh     = (const float*)d_in[11];
  const float* Wcc    = (const float*)d_in[12];
  const float* Wcp    = (const float*)d_in[13];
  const float* bc     = (const float*)d_in[14];
  const float* Wo     = (const float*)d_in[15];
  const float* bo     = (const float*)d_in[16];
  float* out = (float*)d_out;

  bar_init<<<dim3(1), dim3(256), 0, stream>>>();

  void* args[] = { (void*)&inputs, (void*)&Ag, (void*)&Wk, (void*)&Wr, (void*)&bls,
                   (void*)&Wgh, (void*)&bgh, (void*)&Wgc, (void*)&bgc,
                   (void*)&Whc, (void*)&Whp, (void*)&bh,
                   (void*)&Wcc, (void*)&Wcp, (void*)&bc,
                   (void*)&Wo, (void*)&bo, (void*)&out };
  hipError_t err = hipLaunchCooperativeKernel((void*)gg_kernel, dim3(NBLK), dim3(NTHR),
                                              args, 0, stream);
  if (err != hipSuccess) {
    (void)hipGetLastError();   // clear; fall back (grid 256 <= 256 CUs, 1 block/CU)
    gg_kernel<<<dim3(NBLK), dim3(NTHR), 0, stream>>>(inputs, Ag, Wk, Wr, bls,
                                                     Wgh, bgh, Wgc, bgc,
                                                     Whc, Whp, bh, Wcc, Wcp, bc,
                                                     Wo, bo, out);
  }
}

// Round 7
// 5590.243 us; speedup vs baseline: 1.1816x; 1.1816x over previous
//
#include <hip/hip_runtime.h>

// Graph-gated LSTM recurrence, persistent cooperative kernel (round 10).
// R9 post-mortem: 1024thr/4 waves-per-SIMD REGRESSED (6.01->6.61ms):
// VALUBusy and MfmaUtil fell, LDS conflicts doubled, VGPR squeezed to 64.
// TLP beyond 2 waves/SIMD is falsified as a lever -> revert to R8 config
// (512 thr, VGPR 128, 16.5us/step best). Remaining-floor theory: (a) the
// relay flag tree adds a full LLC hop (~1.5-2us) to every step and relay
// blocks carry asymmetric duty; (b) the all-256-producer gate re-couples
// max-block skew in front of the MFMA phase. But wave wv only consumes
// K-slice [wv*512,wv*512+512) = blocks [wv*32,wv*32+32) -- exactly one
// 128B flag line. This round:
//  1. Relay/gflag DELETED. Per-wave direct gate: each wave polls its own
//     32 producer flags (lanes 0-31, one LLC line, 256 pollers/line --
//     proven scale). Publish->observe is now ONE hop, and early waves
//     start MFMA while slow producers finish (skew absorbed into MFMA).
//  2. x(t+1) prefetch hoisted above the gate (R9's one good idea).
//  3. Everything else IDENTICAL to proven R8: write-through generation-
//     indexed X at LLC (no fences ever), publish-before-out, 512 threads.
// Predicted: 16.5us/step -> 12.5-14.5us/step (4.6-5.3ms). If >=5.6ms,
// chain-depth/skew is falsified too -> keep-live phase ablation next.

#define NN   4096
#define TT   365
#define FF   16
#define HH   20
#define G4   80
#define RPB  16     // nodes per block
#define NBLK 256
#define NTHR 512    // 8 waves, 2 per SIMD (R8-proven best)
#define NWV  8
#define XRG  42     // rows per generation: 40 data + 1 pad(read) + 1 guard
#define KSPL 512    // K-slice per wave (8 waves * 512 = 4096)
#define NFRG 16     // A fragments per wave (KSPL/32)

typedef float f4 __attribute__((ext_vector_type(4)));
typedef short s8v __attribute__((ext_vector_type(8)));

// 365 generations * 42 rows * 4096 cols * 2B = 125.6MB; lives in LLC.
__device__ __attribute__((aligned(16))) unsigned short g_X[(size_t)TT * XRG * NN];
__device__ unsigned g_flag[NBLK];        // raw: block b published X(gen)

struct __align__(16) Smem {
  float WkT[G4][FF];              // lstm kernel, transposed
  float WrT[G4][HH];              // lstm recurrent, transposed
  float WghT[HH][HH]; float WgcT[HH][HH];
  float WhcT[HH][HH]; float WhpT[HH][HH];
  float WccT[HH][HH]; float WcpT[HH][HH];
  float Wout[HH];
  float bias[G4];
  float bgh[HH]; float bgc[HH]; float bhv[HH]; float bcv[HH];
  float bout; float pad0[3];
  float hprev[RPB][HH]; float cprev[RPB][HH];
  float hcur[RPB][HH];  float ccur[RPB][HH];
  float hg[RPB][HH];    float cg[RPB][HH];
  float cen[2 * HH];              // X centering values
  float SA[RPB];                  // per-row sum of bf16(A)
  float sAp[32][16];              // 8 waves * 4 quads
  float part[NWV][3][16][17];     // per-wave MFMA partials (~26KB)
};                                // ~57 KB total

__device__ inline float sigm(float x) { return 1.f / (1.f + __expf(-x)); }
__device__ inline float tanh_f(float x) { return 2.f / (1.f + __expf(-2.f * x)) - 1.f; }

__device__ inline unsigned short f2bf(float f) {   // RNE fp32->bf16
  unsigned u = __float_as_uint(f);
  u = u + 0x7FFFu + ((u >> 16) & 1u);
  return (unsigned short)(u >> 16);
}
__device__ inline float bf2f(unsigned short u) {
  return __uint_as_float(((unsigned)u) << 16);
}

__device__ inline void load_x(const float* __restrict__ inputs, int nb0, int t,
                              int tid, f4* x) {
  const float* xr = inputs + ((size_t)(nb0 + (tid & 15)) * TT + t) * FF;
  x[0] = *(const f4*)(xr);
  x[1] = *(const f4*)(xr + 4);
  x[2] = *(const f4*)(xr + 8);
  x[3] = *(const f4*)(xr + 12);
}

// LSTM cell for the block's 16 nodes; x pre-loaded for node tid&15.
__device__ inline void lstm_cells_x(Smem& sm, const f4* x, int tid) {
  const int n = tid & 15;
  const f4* hpr = (const f4*)sm.hprev[n];
  const f4 hp0 = hpr[0], hp1 = hpr[1], hp2 = hpr[2], hp3 = hpr[3], hp4 = hpr[4];
  for (int idx = tid; idx < RPB * HH; idx += NTHR) {
    const int h = idx >> 4;
    float z[4];
#pragma unroll
    for (int g = 0; g < 4; g++) {
      const int col = g * HH + h;
      const f4* wk = (const f4*)sm.WkT[col];
      f4 acc = x[0] * wk[0] + x[1] * wk[1] + x[2] * wk[2] + x[3] * wk[3];
      const f4* wr = (const f4*)sm.WrT[col];
      acc += hp0 * wr[0] + hp1 * wr[1] + hp2 * wr[2] + hp3 * wr[3] + hp4 * wr[4];
      z[g] = sm.bias[col] + acc[0] + acc[1] + acc[2] + acc[3];
    }
    const float co = sm.cprev[n][h];
    const float cn = sigm(z[1]) * co + sigm(z[0]) * tanh_f(z[2]);
    const float hn = sigm(z[3]) * tanh_f(cn);
    sm.hcur[n][h] = hn;
    sm.ccur[n][h] = cn;
  }
}

// X^T[j][node] (bf16, centered) for generation `gen`, from current hprev/cprev.
// Agent-scope write-through stores: X lives only at the LLC, never dirty in L2.
__device__ inline void produce_X(Smem& sm, int gen, int nb0, int tid) {
  for (int idx = tid; idx < 8 * 2 * HH; idx += NTHR) {   // 320 items
    const int p = idx & 7, j = idx >> 3;                 // j in [0,40)
    const int n0 = p * 2;
    const f4* w; float b0; const f4* s0; const f4* s1;
    if (j < HH) {
      w = (const f4*)sm.WghT[j];     b0 = sm.bgh[j];
      s0 = (const f4*)sm.hprev[n0];  s1 = (const f4*)sm.hprev[n0 + 1];
    } else {
      w = (const f4*)sm.WgcT[j-HH];  b0 = sm.bgc[j - HH];
      s0 = (const f4*)sm.cprev[n0];  s1 = (const f4*)sm.cprev[n0 + 1];
    }
    const f4 w0 = w[0], w1 = w[1], w2 = w[2], w3 = w[3], w4 = w[4];
    f4 a0 = s0[0]*w0 + s0[1]*w1 + s0[2]*w2 + s0[3]*w3 + s0[4]*w4;
    f4 a1 = s1[0]*w0 + s1[1]*w1 + s1[2]*w2 + s1[3]*w3 + s1[4]*w4;
    const float c0 = sm.cen[j];
    const unsigned short lo = f2bf(b0 + a0[0] + a0[1] + a0[2] + a0[3] - c0);
    const unsigned short hi = f2bf(b0 + a1[0] + a1[1] + a1[2] + a1[3] - c0);
    const unsigned v = (unsigned)lo | ((unsigned)hi << 16);
    unsigned* dst = (unsigned*)(g_X + (((size_t)gen * XRG + j) << 12) + (unsigned)(nb0 + n0));
    __hip_atomic_store(dst, v, __ATOMIC_RELAXED, __HIP_MEMORY_SCOPE_AGENT);
  }
}

// All X stores of this block drained to the coherence point, then one flag.
__device__ inline void publish(int tid, unsigned gen) {
  asm volatile("s_waitcnt vmcnt(0)" ::: "memory");  // write-through stores at LLC
  __syncthreads();                                  // all waves drained
  if (tid == 0)
    __hip_atomic_store(&g_flag[blockIdx.x], gen,
                       __ATOMIC_RELAXED, __HIP_MEMORY_SCOPE_AGENT);
}

__global__ void bar_init() {
  const int i = threadIdx.x;
  if (i < NBLK)
    __hip_atomic_store(&g_flag[i], 0u, __ATOMIC_RELAXED, __HIP_MEMORY_SCOPE_AGENT);
}

__global__ void __launch_bounds__(NTHR, 2)
gg_kernel(const float* __restrict__ inputs, const float* __restrict__ Ag,
          const float* __restrict__ Wk, const float* __restrict__ Wr, const float* __restrict__ bls,
          const float* __restrict__ Wgh, const float* __restrict__ bgh,
          const float* __restrict__ Wgc, const float* __restrict__ bgc,
          const float* __restrict__ Whc, const float* __restrict__ Whp, const float* __restrict__ bh,
          const float* __restrict__ Wcc, const float* __restrict__ Wcp, const float* __restrict__ bc,
          const float* __restrict__ Wo, const float* __restrict__ bo,
          float* __restrict__ out) {
  __shared__ Smem sm;
  const int tid  = threadIdx.x;
  const int nb0  = blockIdx.x * RPB;
  const int lane = tid & 63;
  const int wv   = tid >> 6;          // 0..7
  const int li   = lane & 15;
  const int quad = lane >> 4;

  // ---- one-time: weights (transposed) into LDS ----
  for (int i = tid; i < FF * G4; i += NTHR) sm.WkT[i % G4][i / G4] = Wk[i];
  for (int i = tid; i < HH * G4; i += NTHR) sm.WrT[i % G4][i / G4] = Wr[i];
  for (int i = tid; i < HH * HH; i += NTHR) {
    const int r = i / HH, c = i % HH;
    sm.WghT[c][r] = Wgh[i]; sm.WgcT[c][r] = Wgc[i];
    sm.WhcT[c][r] = Whc[i]; sm.WhpT[c][r] = Whp[i];
    sm.WccT[c][r] = Wcc[i]; sm.WcpT[c][r] = Wcp[i];
  }
  for (int i = tid; i < G4; i += NTHR) sm.bias[i] = bls[i];
  if (tid < HH) { sm.bgh[tid] = bgh[tid]; sm.bgc[tid] = bgc[tid]; sm.bhv[tid] = bh[tid]; sm.bcv[tid] = bc[tid]; sm.Wout[tid] = Wo[tid]; }
  if (tid == 0) sm.bout = bo[0];
  for (int i = tid; i < RPB * HH; i += NTHR) { (&sm.hprev[0][0])[i] = 0.f; (&sm.cprev[0][0])[i] = 0.f; }
  __syncthreads();

  // cen[j] = b[j] + 0.5 * column-sum(W): X values cluster here
  if (tid < 2 * HH) {
    const int j = tid;
    float s = 0.f;
    if (j < HH) { for (int h = 0; h < HH; h++) s += sm.WghT[j][h]; s = sm.bgh[j] + 0.5f * s; }
    else        { for (int h = 0; h < HH; h++) s += sm.WgcT[j - HH][h]; s = sm.bgc[j - HH] + 0.5f * s; }
    sm.cen[j] = s;
  }

  // ---- one-time: A rows -> VGPR fragments (bf16) + row sums of bf16(A) ----
  s8v afrag[NFRG];
  {
    const float* Arow = Ag + (size_t)(nb0 + li) * NN + (size_t)(wv * KSPL + quad * 8);
    double ds = 0.0;
#pragma unroll
    for (int i = 0; i < NFRG; i++) {
      const f4 v0 = *(const f4*)(Arow + i * 32);
      const f4 v1 = *(const f4*)(Arow + i * 32 + 4);
      s8v tb;
      tb[0] = (short)f2bf(v0[0]); tb[1] = (short)f2bf(v0[1]);
      tb[2] = (short)f2bf(v0[2]); tb[3] = (short)f2bf(v0[3]);
      tb[4] = (short)f2bf(v1[0]); tb[5] = (short)f2bf(v1[1]);
      tb[6] = (short)f2bf(v1[2]); tb[7] = (short)f2bf(v1[3]);
      afrag[i] = tb;
#pragma unroll
      for (int e = 0; e < 8; e++) ds += (double)bf2f((unsigned short)tb[e]);
    }
    sm.sAp[wv * 4 + quad][li] = (float)ds;
  }
  __syncthreads();
  if (tid < RPB) {
    float s = 0.f;
#pragma unroll
    for (int g = 0; g < 32; g++) s += sm.sAp[g][tid];
    sm.SA[tid] = s;
  }

  // ---- warm phase: T LSTM steps, block-local, x prefetched one step ahead ----
  f4 xa[4], xb[4];
  load_x(inputs, nb0, 0, tid, xa);
  for (int t = 0; t < TT; t++) {
    if (t + 1 < TT) load_x(inputs, nb0, t + 1, tid, xb);
    __syncthreads();
    lstm_cells_x(sm, xa, tid);
    __syncthreads();
    for (int i = tid; i < RPB * HH; i += NTHR) {
      (&sm.hprev[0][0])[i] = (&sm.hcur[0][0])[i];
      (&sm.cprev[0][0])[i] = (&sm.ccur[0][0])[i];
    }
    xa[0] = xb[0]; xa[1] = xb[1]; xa[2] = xb[2]; xa[3] = xb[3];
  }
  __syncthreads();

  // prologue: publish X_1, then LSTM(t=1) while other blocks finish
  produce_X(sm, 1, nb0, tid);
  publish(tid, 1u);
  load_x(inputs, nb0, 1, tid, xa);
  lstm_cells_x(sm, xa, tid);

  // ---- main recurrence: t = 1..364 ----
  for (int t = 1; t < TT; t++) {
    // prefetch x(t+1) into regs: latency overlaps the gate poll below
    if (t + 1 < TT) load_x(inputs, nb0, t + 1, tid, xa);

    // per-wave direct gate: this wave's K-slice [wv*512,(wv+1)*512) is
    // produced by blocks [wv*32, wv*32+32) -- one flag per lane (0..31),
    // exactly one 128B LLC line per wave. No relay, one hop, and early
    // waves start MFMA while slow producers finish (skew absorption).
    for (;;) {
      int ok = 1;
      if (lane < 32)
        ok = (__hip_atomic_load(&g_flag[(wv << 5) + lane], __ATOMIC_RELAXED,
                                __HIP_MEMORY_SCOPE_AGENT) >= (unsigned)t);
      if (__all(ok)) break;
      __builtin_amdgcn_s_sleep(1);
    }
    asm volatile("" ::: "memory");
    __builtin_amdgcn_sched_barrier(0);

    // MFMA partials from generation-t X (fresh addresses, LLC/L2-served)
    const unsigned short* Xt = g_X + (((size_t)t * XRG) << 12)
                             + (size_t)(wv * KSPL + quad * 8);
#pragma unroll
    for (int c = 0; c < 3; c++) {
      int row = c * 16 + li;
      if (row >= 2 * HH) row = 2 * HH;   // pad lanes read row 40 (discarded)
      const unsigned short* Xrow = Xt + ((size_t)row << 12);
      f4 a0 = {0.f, 0.f, 0.f, 0.f}, a1 = a0, a2 = a0, a3 = a0;
#pragma unroll
      for (int i = 0; i < NFRG; i += 4) {
        a0 = __builtin_amdgcn_mfma_f32_16x16x32_bf16(afrag[i + 0], *(const s8v*)(Xrow + (i + 0) * 32), a0, 0, 0, 0);
        a1 = __builtin_amdgcn_mfma_f32_16x16x32_bf16(afrag[i + 1], *(const s8v*)(Xrow + (i + 1) * 32), a1, 0, 0, 0);
        a2 = __builtin_amdgcn_mfma_f32_16x16x32_bf16(afrag[i + 2], *(const s8v*)(Xrow + (i + 2) * 32), a2, 0, 0, 0);
        a3 = __builtin_amdgcn_mfma_f32_16x16x32_bf16(afrag[i + 3], *(const s8v*)(Xrow + (i + 3) * 32), a3, 0, 0, 0);
      }
      const f4 ac = (a0 + a1) + (a2 + a3);
#pragma unroll
      for (int r = 0; r < 4; r++) sm.part[wv][c][quad * 4 + r][li] = ac[r];
    }
    __syncthreads();

    // cross-wave reduce (8 partials) + centering + tanh -> hg/cg
#pragma unroll
    for (int p = 0; p < 2; p++) {
      const int idx = tid + NTHR * p;
      if (idx < 768) {
        const int c = idx >> 8, rc = idx & 255, r = rc >> 4, col = rc & 15;
        const int gc = c * 16 + col;
        if (gc < 2 * HH) {
          float s = 0.f;
#pragma unroll
          for (int w = 0; w < NWV; w++) s += sm.part[w][c][r][col];
          const float v = s + sm.SA[r] * sm.cen[gc];
          const float tv = tanh_f(v);
          if (gc < HH) sm.hg[r][gc] = tv; else sm.cg[r][gc - HH] = tv;
        }
      }
    }
    __syncthreads();

    // update stage: h_upd = sig(hcur@Whc + hg@Whp + bh); c_upd likewise
    for (int idx = tid; idx < 2 * RPB * HH; idx += NTHR) {
      int q = idx; int cpath = 0;
      if (q >= RPB * HH) { q -= RPB * HH; cpath = 1; }
      const int n = q & 15, h = q >> 4;
      const f4* cur = (const f4*)(cpath ? sm.ccur[n] : sm.hcur[n]);
      const f4* gr2 = (const f4*)(cpath ? sm.cg[n] : sm.hg[n]);
      const f4* w1  = (const f4*)(cpath ? sm.WccT[h] : sm.WhcT[h]);
      const f4* w2  = (const f4*)(cpath ? sm.WcpT[h] : sm.WhpT[h]);
      f4 acc = cur[0]*w1[0] + cur[1]*w1[1] + cur[2]*w1[2] + cur[3]*w1[3] + cur[4]*w1[4];
      acc   += gr2[0]*w2[0] + gr2[1]*w2[1] + gr2[2]*w2[2] + gr2[3]*w2[3] + gr2[4]*w2[4];
      const float b0 = cpath ? sm.bcv[h] : sm.bhv[h];
      const float v = sigm(b0 + acc[0] + acc[1] + acc[2] + acc[3]);
      if (cpath) sm.cprev[n][h] = v; else sm.hprev[n][h] = v;
    }
    __syncthreads();

    // publish FIRST (inter-block critical path), out-write after
    if (t < TT - 1) {
      produce_X(sm, t + 1, nb0, tid);              // X generation t+1
      publish(tid, (unsigned)(t + 1));             // drain + flag
    }

    if (tid < RPB) {                               // out[t-1, node] = h_upd @ W_out + b
      float acc = sm.bout;
#pragma unroll
      for (int h2 = 0; h2 < HH; h2++) acc += sm.hprev[tid][h2] * sm.Wout[h2];
      out[(size_t)(t - 1) * NN + nb0 + tid] = acc;
    }

    if (t < TT - 1) {
      lstm_cells_x(sm, xa, tid);                   // LSTM(t+1), x prefetched at top
    }
  }
}

extern "C" void kernel_launch(void* const* d_in, const int* in_sizes, int n_in,
                              void* d_out, int out_size, void* d_ws, size_t ws_size,
                              hipStream_t stream) {
  (void)in_sizes; (void)n_in; (void)out_size; (void)d_ws; (void)ws_size;
  const float* inputs = (const float*)d_in[0];
  const float* Ag     = (const float*)d_in[1];
  const float* Wk     = (const float*)d_in[2];
  const float* Wr     = (const float*)d_in[3];
  const float* bls    = (const float*)d_in[4];
  const float* Wgh    = (const float*)d_in[5];
  const float* bgh    = (const float*)d_in[6];
  const float* Wgc    = (const float*)d_in[7];
  const float* bgc    = (const float*)d_in[8];
  const float* Whc    = (const float*)d_in[9];
  const float* Whp    = (const float*)d_in[10];
  const float* bh     = (const float*)d_in[11];
  const float* Wcc    = (const float*)d_in[12];
  const float* Wcp    = (const float*)d_in[13];
  const float* bc     = (const float*)d_in[14];
  const float* Wo     = (const float*)d_in[15];
  const float* bo     = (const float*)d_in[16];
  float* out = (float*)d_out;

  bar_init<<<dim3(1), dim3(256), 0, stream>>>();

  void* args[] = { (void*)&inputs, (void*)&Ag, (void*)&Wk, (void*)&Wr, (void*)&bls,
                   (void*)&Wgh, (void*)&bgh, (void*)&Wgc, (void*)&bgc,
                   (void*)&Whc, (void*)&Whp, (void*)&bh,
                   (void*)&Wcc, (void*)&Wcp, (void*)&bc,
                   (void*)&Wo, (void*)&bo, (void*)&out };
  hipError_t err = hipLaunchCooperativeKernel((void*)gg_kernel, dim3(NBLK), dim3(NTHR),
                                              args, 0, stream);
  if (err != hipSuccess) {
    (void)hipGetLastError();   // clear; fall back (grid 256 <= 256 CUs, 1 block/CU)
    gg_kernel<<<dim3(NBLK), dim3(NTHR), 0, stream>>>(inputs, Ag, Wk, Wr, bls,
                                                     Wgh, bgh, Wgc, bgc,
                                                     Whc, Whp, bh, Wcc, Wcp, bc,
                                                     Wo, bo, out);
  }
}